// Round 4
// baseline (824.046 us; speedup 1.0000x reference)
//
#include <hip/hip_runtime.h>
#include <cstdint>
#include <cstddef>

#define HEADS 16
#define DH 64
#define BH 28
#define BWW 28
#define BATCH 32
#define HID 1024
#define M_ROWS 25088           // 32*28*28
#define ALPHA_C 0.082847664332725576f
#define EPS_C 1e-5f

typedef unsigned short ushort_t;
typedef __attribute__((ext_vector_type(8))) short bf16x8;     // 8 bf16 in 4 VGPRs
typedef __attribute__((ext_vector_type(4))) float f32x4;

__device__ inline unsigned short f2bf(float f) {
  unsigned int u = __builtin_bit_cast(unsigned int, f);
  u = (u + 0x7fffu + ((u >> 16) & 1u)) >> 16;   // RNE
  return (unsigned short)u;
}
__device__ inline float bf2f(unsigned short h) {
  unsigned int u = ((unsigned int)h) << 16;
  return __builtin_bit_cast(float, u);
}

// -------- dtype detect (bf16 vs fp32 bits) + zero stats --------
__global__ __launch_bounds__(256) void detect_k(const ushort_t* __restrict__ x,
                                                const ushort_t* __restrict__ qw,
                                                float* __restrict__ stats,
                                                int* __restrict__ flagp) {
  int tid = threadIdx.x;
  int big = 0;
  #pragma unroll
  for (int j = 0; j < 4; ++j) {
    float a = fabsf(bf2f(x[tid * 4 + j]));
    float b = fabsf(bf2f(qw[tid * 4 + j]));
    if (!(a < 1e3f)) big++;            // catches huge, Inf, NaN
    if (!(b < 1e3f)) big++;
  }
  __shared__ int cnt;
  if (tid == 0) cnt = 0;
  __syncthreads();
  if (big) atomicAdd(&cnt, big);
  __syncthreads();
  if (tid == 0) *flagp = (cnt == 0) ? 1 : 0;   // 1 = inputs are bf16
  stats[tid] = 0.f; stats[tid + 256] = 0.f; stats[tid + 512] = 0.f; stats[tid + 768] = 0.f;
}

// -------- zero vsum (917504 floats; grid 3584x256) --------
__global__ __launch_bounds__(256) void zero_k(float* __restrict__ p) {
  p[(size_t)blockIdx.x * 256 + threadIdx.x] = 0.f;
}

// -------- canonicalize x -> bf16 (flag-branched) --------
__global__ __launch_bounds__(256) void conv_x_k(const void* __restrict__ src,
                                                const int* __restrict__ flagp,
                                                ushort_t* __restrict__ dst, long n8) {
  long i = (long)blockIdx.x * 256 + threadIdx.x;
  if (i >= n8) return;
  long e = i * 8;
  if (*flagp) {
    *(uint4*)(dst + e) = *(const uint4*)((const ushort_t*)src + e);
  } else {
    const float* sf = (const float*)src;
    float4 a = *(const float4*)(sf + e);
    float4 b = *(const float4*)(sf + e + 4);
    union { ushort_t u[8]; uint4 v; } o;
    o.u[0] = f2bf(a.x); o.u[1] = f2bf(a.y); o.u[2] = f2bf(a.z); o.u[3] = f2bf(a.w);
    o.u[4] = f2bf(b.x); o.u[5] = f2bf(b.y); o.u[6] = f2bf(b.z); o.u[7] = f2bf(b.w);
    *(uint4*)(dst + e) = o.v;
  }
}

// -------- transpose either dtype -> bf16: dst[c*R+r] = src[r*C+c] --------
__global__ void transpose_any_k(const void* __restrict__ src, const int* __restrict__ flagp,
                                ushort_t* __restrict__ dst, int R, int C) {
  __shared__ float tile[32][33];
  int isbf = *flagp;
  int c0 = blockIdx.x * 32, r0 = blockIdx.y * 32;
  int tx = threadIdx.x, ty = threadIdx.y;
  const ushort_t* sb = (const ushort_t*)src;
  const float* sf = (const float*)src;
  #pragma unroll
  for (int i = ty; i < 32; i += 8) {
    size_t idx = (size_t)(r0 + i) * C + (c0 + tx);
    tile[i][tx] = isbf ? bf2f(sb[idx]) : sf[idx];
  }
  __syncthreads();
  #pragma unroll
  for (int i = ty; i < 32; i += 8)
    dst[(size_t)(c0 + i) * R + (r0 + tx)] = f2bf(tile[tx][i]);
}

#define BK 32

// -------- GEMM1 + fused qkv epilogue --------
// C = x @ qkv_w  (M=25088, N=3072, K=1024), never materialized. Epilogue per
// 64-col group (wave-uniform t, head n): +img*ALPHA; t=0/2 -> RoPE (pairs are
// adjacent ni registers; freq idx = fr; pos = h for ni<2 else w), store bf16
// (b,n,h,w,d); t=1 -> atomicAdd into fp32 vsum[b,n,w,d].
__global__ __launch_bounds__(256) void gemm_qkv_k(const void* __restrict__ x_raw,
                                                  const ushort_t* __restrict__ x_bf,
                                                  const ushort_t* __restrict__ Bt,
                                                  const void* __restrict__ img,
                                                  const int* __restrict__ flagp,
                                                  ushort_t* __restrict__ qbuf,
                                                  ushort_t* __restrict__ kbuf,
                                                  float* __restrict__ vsum) {
  __shared__ ushort_t As[128 * BK];
  __shared__ ushort_t Bs[128 * BK];
  const int tid = threadIdx.x;
  const int K = 1024, N = 3072;
  const int ntile = N / 128;
  const int n0 = (blockIdx.x % ntile) * 128;
  const int m0 = (blockIdx.x / ntile) * 128;
  const int lane = tid & 63;
  const int wave = tid >> 6;
  const int wm = (wave >> 1) * 64;
  const int wn = (wave & 1) * 64;
  const int fr = lane & 15;
  const int fq = lane >> 4;
  const int isbf = *flagp;
  const ushort_t* A = isbf ? (const ushort_t*)x_raw : x_bf;

  f32x4 acc[4][4] = {};
  const int srow = tid >> 2;
  const int skk  = (tid & 3) * 8;

  for (int k0 = 0; k0 < K; k0 += BK) {
    __syncthreads();
    const ushort_t* a0 = A + (size_t)(m0 + srow) * K + k0 + skk;
    const ushort_t* b0 = Bt + (size_t)(n0 + srow) * K + k0 + skk;
    __builtin_amdgcn_global_load_lds((const __attribute__((address_space(1))) unsigned int*)a0,
        (__attribute__((address_space(3))) unsigned int*)(As + tid * 8), 16, 0, 0);
    __builtin_amdgcn_global_load_lds((const __attribute__((address_space(1))) unsigned int*)(a0 + (size_t)64 * K),
        (__attribute__((address_space(3))) unsigned int*)(As + 2048 + tid * 8), 16, 0, 0);
    __builtin_amdgcn_global_load_lds((const __attribute__((address_space(1))) unsigned int*)b0,
        (__attribute__((address_space(3))) unsigned int*)(Bs + tid * 8), 16, 0, 0);
    __builtin_amdgcn_global_load_lds((const __attribute__((address_space(1))) unsigned int*)(b0 + (size_t)64 * K),
        (__attribute__((address_space(3))) unsigned int*)(Bs + 2048 + tid * 8), 16, 0, 0);
    __syncthreads();

    bf16x8 af[4], bfv[4];
    #pragma unroll
    for (int i = 0; i < 4; ++i)
      af[i] = *reinterpret_cast<const bf16x8*>(&As[(wm + i * 16 + fr) * BK + fq * 8]);
    #pragma unroll
    for (int i = 0; i < 4; ++i)
      bfv[i] = *reinterpret_cast<const bf16x8*>(&Bs[(wn + i * 16 + fr) * BK + fq * 8]);
    #pragma unroll
    for (int mi = 0; mi < 4; ++mi)
      #pragma unroll
      for (int ni = 0; ni < 4; ++ni)
        acc[mi][ni] = __builtin_amdgcn_mfma_f32_16x16x32_bf16(af[mi], bfv[ni], acc[mi][ni], 0, 0, 0);
  }

  // ---- fused epilogue ----
  const int colg = n0 + wn;              // 64-aligned
  const int t = colg >> 10;              // 0=q 1=v 2=k (wave-uniform)
  const int n = (colg & 1023) >> 6;      // head
  const float gamma = 1.0f - exp2f(-5.0f - (float)n);
  const float invf = powf(10000.0f, -(float)fr / 16.0f);
  const ushort_t* imgb = (const ushort_t*)img;
  const float* imgf = (const float*)img;

  #pragma unroll
  for (int mi = 0; mi < 4; ++mi) {
    #pragma unroll
    for (int r = 0; r < 4; ++r) {
      int m = m0 + wm + mi * 16 + fq * 4 + r;
      int b = m / 784, rem = m % 784;
      int h = rem / 28, w = rem % 28;
      size_t ibase = (size_t)m * HID + n * DH + fr;
      float v0 = acc[mi][0][r] + (isbf ? bf2f(imgb[ibase])      : imgf[ibase])      * ALPHA_C;
      float v1 = acc[mi][1][r] + (isbf ? bf2f(imgb[ibase + 16]) : imgf[ibase + 16]) * ALPHA_C;
      float v2 = acc[mi][2][r] + (isbf ? bf2f(imgb[ibase + 32]) : imgf[ibase + 32]) * ALPHA_C;
      float v3 = acc[mi][3][r] + (isbf ? bf2f(imgb[ibase + 48]) : imgf[ibase + 48]) * ALPHA_C;
      if (t == 1) {
        float* vb = vsum + ((((size_t)b * HEADS + n) * BWW + w) * DH) + fr;
        atomicAdd(vb,      v0);
        atomicAdd(vb + 16, v1);
        atomicAdd(vb + 32, v2);
        atomicAdd(vb + 48, v3);
      } else {
        if (t == 2) { v0 *= gamma; v1 *= gamma; v2 *= gamma; v3 *= gamma; }
        float snh, csh, snw, csw;
        __sincosf((float)h * invf, &snh, &csh);
        __sincosf((float)w * invf, &snw, &csw);
        float o0 = v0 * csh - v1 * snh;    // d=fr      (sgn -, partner d+16)
        float o1 = v1 * csh + v0 * snh;    // d=fr+16   (sgn +, partner d-16)
        float o2 = v2 * csw - v3 * snw;    // d=fr+32
        float o3 = v3 * csw + v2 * snw;    // d=fr+48
        ushort_t* dst = (t == 0 ? qbuf : kbuf) +
            (((((size_t)b * HEADS + n) * BH + h) * BWW + w) * DH) + fr;
        dst[0]  = f2bf(o0);
        dst[16] = f2bf(o1);
        dst[32] = f2bf(o2);
        dst[48] = f2bf(o3);
      }
    }
  }
}

// -------- attention per (b,n,h): S=Q K^T (28x28), out = S @ vsum --------
__global__ __launch_bounds__(256) void attn_k(const ushort_t* __restrict__ qbuf,
                                              const ushort_t* __restrict__ kbuf,
                                              const float* __restrict__ vsum,
                                              ushort_t* __restrict__ out,
                                              float* __restrict__ stats) {
  __shared__ float Qs[BWW][DH + 1];
  __shared__ float Ks[BWW][DH + 1];
  __shared__ float Vs[BWW][DH + 1];
  __shared__ float Ss[BWW][BWW + 1];
  int blk = blockIdx.x;
  int h = blk % BH;
  int n = (blk / BH) % HEADS;
  int b = blk / (BH * HEADS);
  int tid = threadIdx.x;
  size_t obase = ((((size_t)b * HEADS + n) * BH + h) * BWW) * DH;  // also q/k base
  size_t vbase = (((size_t)b * HEADS + n) * BWW) * DH;

  for (int e = tid; e < BWW * DH; e += 256) {
    int r = e / DH, c = e % DH;
    Qs[r][c] = bf2f(qbuf[obase + e]);
    Ks[r][c] = bf2f(kbuf[obase + e]);
    Vs[r][c] = vsum[vbase + e];
  }
  __syncthreads();
  for (int e = tid; e < BWW * BWW; e += 256) {
    int x = e / BWW, z = e % BWW;
    float acc = 0.f;
    #pragma unroll
    for (int dd = 0; dd < DH; ++dd) acc += Qs[x][dd] * Ks[z][dd];
    Ss[x][z] = acc;
  }
  __syncthreads();
  float lsum = 0.f, lsq = 0.f;
  for (int e = tid; e < BWW * DH; e += 256) {
    int w = e / DH, dd = e % DH;
    float acc = 0.f;
    #pragma unroll
    for (int y = 0; y < BWW; ++y) acc += Ss[w][y] * Vs[y][dd];
    out[obase + e] = f2bf(acc);
    lsum += acc; lsq += acc * acc;
  }
  #pragma unroll
  for (int off = 32; off > 0; off >>= 1) {
    lsum += __shfl_down(lsum, off);
    lsq  += __shfl_down(lsq, off);
  }
  __shared__ float rs[4][2];
  int lane = tid & 63, wv = tid >> 6;
  if (lane == 0) { rs[wv][0] = lsum; rs[wv][1] = lsq; }
  __syncthreads();
  if (tid == 0) {
    float s  = rs[0][0] + rs[1][0] + rs[2][0] + rs[3][0];
    float q2 = rs[0][1] + rs[1][1] + rs[2][1] + rs[3][1];
    atomicAdd(&stats[(b * HEADS + n) * 2], s);
    atomicAdd(&stats[(b * HEADS + n) * 2 + 1], q2);
  }
}

// -------- GroupNorm apply + relayout to (b,H,W,hid) bf16 --------
__global__ __launch_bounds__(256) void gn_k(const ushort_t* __restrict__ out,
                                            const float* __restrict__ stats,
                                            const void* __restrict__ gn_w,
                                            const void* __restrict__ gn_b,
                                            const int* __restrict__ flagp,
                                            ushort_t* __restrict__ xo) {
  size_t idx = (size_t)blockIdx.x * 256 + threadIdx.x;   // (b,n,h,w,d)
  int d = idx & 63;
  size_t rest = idx >> 6;
  int w = rest % BWW; rest /= BWW;
  int h = rest % BH;  rest /= BH;
  int n = rest % HEADS;
  int b = (int)(rest / HEADS);
  int isbf = *flagp;
  float gw = isbf ? bf2f(((const ushort_t*)gn_w)[n]) : ((const float*)gn_w)[n];
  float gb = isbf ? bf2f(((const ushort_t*)gn_b)[n]) : ((const float*)gn_b)[n];
  float s  = stats[(b * HEADS + n) * 2];
  float q2 = stats[(b * HEADS + n) * 2 + 1];
  const float Ninv = 1.0f / (float)(BH * BWW * DH);
  float mu = s * Ninv;
  float var = q2 * Ninv - mu * mu;
  float rstd = rsqrtf(var + EPS_C);
  float v = (bf2f(out[idx]) - mu) * rstd * gw + gb;
  size_t dst = ((((size_t)b * BH + h) * BWW + w) * HID) + (size_t)n * DH + d;
  xo[dst] = f2bf(v);
}

// -------- plain GEMM (used for GEMM2), dyn output dtype --------
__global__ __launch_bounds__(256) void gemm_bt_k(const ushort_t* __restrict__ A,
                                                 const ushort_t* __restrict__ Bt,
                                                 void* __restrict__ Cv,
                                                 const int* __restrict__ flagp,
                                                 int M, int N, int K) {
  __shared__ ushort_t As[128 * BK];
  __shared__ ushort_t Bs[128 * BK];
  const int tid = threadIdx.x;
  const int ntile = N / 128;
  const int n0 = (blockIdx.x % ntile) * 128;
  const int m0 = (blockIdx.x / ntile) * 128;
  const int lane = tid & 63;
  const int wave = tid >> 6;
  const int wm = (wave >> 1) * 64;
  const int wn = (wave & 1) * 64;
  const int fr = lane & 15;
  const int fq = lane >> 4;

  f32x4 acc[4][4] = {};
  const int srow = tid >> 2;
  const int skk  = (tid & 3) * 8;

  for (int k0 = 0; k0 < K; k0 += BK) {
    __syncthreads();
    const ushort_t* a0 = A + (size_t)(m0 + srow) * K + k0 + skk;
    const ushort_t* b0 = Bt + (size_t)(n0 + srow) * K + k0 + skk;
    __builtin_amdgcn_global_load_lds((const __attribute__((address_space(1))) unsigned int*)a0,
        (__attribute__((address_space(3))) unsigned int*)(As + tid * 8), 16, 0, 0);
    __builtin_amdgcn_global_load_lds((const __attribute__((address_space(1))) unsigned int*)(a0 + (size_t)64 * K),
        (__attribute__((address_space(3))) unsigned int*)(As + 2048 + tid * 8), 16, 0, 0);
    __builtin_amdgcn_global_load_lds((const __attribute__((address_space(1))) unsigned int*)b0,
        (__attribute__((address_space(3))) unsigned int*)(Bs + tid * 8), 16, 0, 0);
    __builtin_amdgcn_global_load_lds((const __attribute__((address_space(1))) unsigned int*)(b0 + (size_t)64 * K),
        (__attribute__((address_space(3))) unsigned int*)(Bs + 2048 + tid * 8), 16, 0, 0);
    __syncthreads();

    bf16x8 af[4], bfv[4];
    #pragma unroll
    for (int i = 0; i < 4; ++i)
      af[i] = *reinterpret_cast<const bf16x8*>(&As[(wm + i * 16 + fr) * BK + fq * 8]);
    #pragma unroll
    for (int i = 0; i < 4; ++i)
      bfv[i] = *reinterpret_cast<const bf16x8*>(&Bs[(wn + i * 16 + fr) * BK + fq * 8]);
    #pragma unroll
    for (int mi = 0; mi < 4; ++mi)
      #pragma unroll
      for (int ni = 0; ni < 4; ++ni)
        acc[mi][ni] = __builtin_amdgcn_mfma_f32_16x16x32_bf16(af[mi], bfv[ni], acc[mi][ni], 0, 0, 0);
  }

  int isbf = *flagp;
  if (isbf) {
    ushort_t* C = (ushort_t*)Cv;
    #pragma unroll
    for (int mi = 0; mi < 4; ++mi)
      #pragma unroll
      for (int r = 0; r < 4; ++r) {
        int m = m0 + wm + mi * 16 + fq * 4 + r;
        ushort_t* crow = C + (size_t)m * N + n0 + wn + fr;
        #pragma unroll
        for (int ni = 0; ni < 4; ++ni) crow[ni * 16] = f2bf(acc[mi][ni][r]);
      }
  } else {
    float* C = (float*)Cv;
    #pragma unroll
    for (int mi = 0; mi < 4; ++mi)
      #pragma unroll
      for (int r = 0; r < 4; ++r) {
        int m = m0 + wm + mi * 16 + fq * 4 + r;
        float* crow = C + (size_t)m * N + n0 + wn + fr;
        #pragma unroll
        for (int ni = 0; ni < 4; ++ni) crow[ni * 16] = acc[mi][ni][r];
      }
  }
}

// -------- launch --------
extern "C" void kernel_launch(void* const* d_in, const int* in_sizes, int n_in,
                              void* d_out, int out_size, void* d_ws, size_t ws_size,
                              hipStream_t stream) {
  const void* x     = d_in[0];
  const void* img   = d_in[1];
  const void* qkv_w = d_in[2];
  const void* o_w   = d_in[3];
  const void* gn_w  = d_in[4];
  const void* gn_b  = d_in[5];

  char* ws = (char*)d_ws;
  // layout (bytes), peak 217,583,872 (round-3-proven budget):
  ushort_t* x_bf  = (ushort_t*)(ws);                 // 51,380,224; dead after gemm1
  ushort_t* xo    = (ushort_t*)(ws);                 // overlays dead x_bf (written by gn_k)
  ushort_t* qbuf  = (ushort_t*)(ws + 51380224);      // 51,380,224
  ushort_t* kbuf  = (ushort_t*)(ws + 102760448);     // 51,380,224
  ushort_t* attn  = (ushort_t*)(ws + 154140672);     // 51,380,224
  float*    vsum  = (float*)(ws + 205520896);        //  3,670,016 (917,504 floats)
  float*    stats = (float*)(ws + 209190912);        //      4,096
  int*      flag  = (int*)(ws + 209195008);          //        256
  ushort_t* w1T   = (ushort_t*)(ws + 209195264);     //  6,291,456
  ushort_t* w2T   = (ushort_t*)(ws + 215486720);     //  2,097,152 (end 217,583,872)

  detect_k<<<1, 256, 0, stream>>>((const ushort_t*)x, (const ushort_t*)qkv_w, stats, flag);
  zero_k<<<3584, 256, 0, stream>>>(vsum);            // 3584*256 = 917,504 exactly
  conv_x_k<<<12544, 256, 0, stream>>>(x, flag, x_bf, 3211264L);
  transpose_any_k<<<dim3(96, 32), dim3(32, 8), 0, stream>>>(qkv_w, flag, w1T, 1024, 3072);
  transpose_any_k<<<dim3(32, 32), dim3(32, 8), 0, stream>>>(o_w, flag, w2T, 1024, 1024);

  gemm_qkv_k<<<196 * 24, 256, 0, stream>>>(x, x_bf, w1T, img, flag, qbuf, kbuf, vsum);

  attn_k<<<BATCH * HEADS * BH, 256, 0, stream>>>(qbuf, kbuf, vsum, attn, stats);
  gn_k<<<100352, 256, 0, stream>>>(attn, stats, gn_w, gn_b, flag, xo);

  gemm_bt_k<<<196 * 8, 256, 0, stream>>>(xo, w2T, d_out, flag, M_ROWS, 1024, 1024);
}

// Round 5
// 694.602 us; speedup vs baseline: 1.1864x; 1.1864x over previous
//
#include <hip/hip_runtime.h>
#include <cstdint>
#include <cstddef>

#define HEADS 16
#define DH 64
#define BH 28
#define BWW 28
#define BATCH 32
#define HID 1024
#define M_ROWS 25088           // 32*28*28
#define ALPHA_C 0.082847664332725576f
#define EPS_C 1e-5f

typedef unsigned short ushort_t;
typedef __attribute__((ext_vector_type(8))) short bf16x8;     // 8 bf16 in 4 VGPRs
typedef __attribute__((ext_vector_type(4))) float f32x4;

__device__ inline unsigned short f2bf(float f) {
  unsigned int u = __builtin_bit_cast(unsigned int, f);
  u = (u + 0x7fffu + ((u >> 16) & 1u)) >> 16;   // RNE
  return (unsigned short)u;
}
__device__ inline float bf2f(unsigned short h) {
  unsigned int u = ((unsigned int)h) << 16;
  return __builtin_bit_cast(float, u);
}

// -------- dtype detect (bf16 vs fp32 bits) + zero stats --------
__global__ __launch_bounds__(256) void detect_k(const ushort_t* __restrict__ x,
                                                const ushort_t* __restrict__ qw,
                                                float* __restrict__ stats,
                                                int* __restrict__ flagp) {
  int tid = threadIdx.x;
  int big = 0;
  #pragma unroll
  for (int j = 0; j < 4; ++j) {
    float a = fabsf(bf2f(x[tid * 4 + j]));
    float b = fabsf(bf2f(qw[tid * 4 + j]));
    if (!(a < 1e3f)) big++;            // catches huge, Inf, NaN
    if (!(b < 1e3f)) big++;
  }
  __shared__ int cnt;
  if (tid == 0) cnt = 0;
  __syncthreads();
  if (big) atomicAdd(&cnt, big);
  __syncthreads();
  if (tid == 0) *flagp = (cnt == 0) ? 1 : 0;   // 1 = inputs are bf16
  stats[tid] = 0.f; stats[tid + 256] = 0.f; stats[tid + 512] = 0.f; stats[tid + 768] = 0.f;
}

// -------- zero vsum (917504 floats; grid 3584x256) --------
__global__ __launch_bounds__(256) void zero_k(float* __restrict__ p) {
  p[(size_t)blockIdx.x * 256 + threadIdx.x] = 0.f;
}

// -------- canonicalize x -> bf16 (flag-branched) --------
__global__ __launch_bounds__(256) void conv_x_k(const void* __restrict__ src,
                                                const int* __restrict__ flagp,
                                                ushort_t* __restrict__ dst, long n8) {
  long i = (long)blockIdx.x * 256 + threadIdx.x;
  if (i >= n8) return;
  long e = i * 8;
  if (*flagp) {
    *(uint4*)(dst + e) = *(const uint4*)((const ushort_t*)src + e);
  } else {
    const float* sf = (const float*)src;
    float4 a = *(const float4*)(sf + e);
    float4 b = *(const float4*)(sf + e + 4);
    union { ushort_t u[8]; uint4 v; } o;
    o.u[0] = f2bf(a.x); o.u[1] = f2bf(a.y); o.u[2] = f2bf(a.z); o.u[3] = f2bf(a.w);
    o.u[4] = f2bf(b.x); o.u[5] = f2bf(b.y); o.u[6] = f2bf(b.z); o.u[7] = f2bf(b.w);
    *(uint4*)(dst + e) = o.v;
  }
}

// -------- transpose either dtype -> bf16: dst[c*R+r] = src[r*C+c] --------
__global__ void transpose_any_k(const void* __restrict__ src, const int* __restrict__ flagp,
                                ushort_t* __restrict__ dst, int R, int C) {
  __shared__ float tile[32][33];
  int isbf = *flagp;
  int c0 = blockIdx.x * 32, r0 = blockIdx.y * 32;
  int tx = threadIdx.x, ty = threadIdx.y;
  const ushort_t* sb = (const ushort_t*)src;
  const float* sf = (const float*)src;
  #pragma unroll
  for (int i = ty; i < 32; i += 8) {
    size_t idx = (size_t)(r0 + i) * C + (c0 + tx);
    tile[i][tx] = isbf ? bf2f(sb[idx]) : sf[idx];
  }
  __syncthreads();
  #pragma unroll
  for (int i = ty; i < 32; i += 8)
    dst[(size_t)(c0 + i) * R + (r0 + tx)] = f2bf(tile[tx][i]);
}

#define BK 32

// -------- GEMM1 + fused qkv epilogue --------
__global__ __launch_bounds__(256) void gemm_qkv_k(const void* __restrict__ x_raw,
                                                  const ushort_t* __restrict__ x_bf,
                                                  const ushort_t* __restrict__ Bt,
                                                  const void* __restrict__ img,
                                                  const int* __restrict__ flagp,
                                                  ushort_t* __restrict__ qbuf,
                                                  ushort_t* __restrict__ kbuf,
                                                  float* __restrict__ vsum) {
  __shared__ ushort_t As[128 * BK];
  __shared__ ushort_t Bs[128 * BK];
  const int tid = threadIdx.x;
  const int K = 1024, N = 3072;
  const int ntile = N / 128;
  const int n0 = (blockIdx.x % ntile) * 128;
  const int m0 = (blockIdx.x / ntile) * 128;
  const int lane = tid & 63;
  const int wave = tid >> 6;
  const int wm = (wave >> 1) * 64;
  const int wn = (wave & 1) * 64;
  const int fr = lane & 15;
  const int fq = lane >> 4;
  const int isbf = *flagp;
  const ushort_t* A = isbf ? (const ushort_t*)x_raw : x_bf;

  f32x4 acc[4][4] = {};
  const int srow = tid >> 2;
  const int skk  = (tid & 3) * 8;

  for (int k0 = 0; k0 < K; k0 += BK) {
    __syncthreads();
    const ushort_t* a0 = A + (size_t)(m0 + srow) * K + k0 + skk;
    const ushort_t* b0 = Bt + (size_t)(n0 + srow) * K + k0 + skk;
    __builtin_amdgcn_global_load_lds((const __attribute__((address_space(1))) unsigned int*)a0,
        (__attribute__((address_space(3))) unsigned int*)(As + tid * 8), 16, 0, 0);
    __builtin_amdgcn_global_load_lds((const __attribute__((address_space(1))) unsigned int*)(a0 + (size_t)64 * K),
        (__attribute__((address_space(3))) unsigned int*)(As + 2048 + tid * 8), 16, 0, 0);
    __builtin_amdgcn_global_load_lds((const __attribute__((address_space(1))) unsigned int*)b0,
        (__attribute__((address_space(3))) unsigned int*)(Bs + tid * 8), 16, 0, 0);
    __builtin_amdgcn_global_load_lds((const __attribute__((address_space(1))) unsigned int*)(b0 + (size_t)64 * K),
        (__attribute__((address_space(3))) unsigned int*)(Bs + 2048 + tid * 8), 16, 0, 0);
    __syncthreads();

    bf16x8 af[4], bfv[4];
    #pragma unroll
    for (int i = 0; i < 4; ++i)
      af[i] = *reinterpret_cast<const bf16x8*>(&As[(wm + i * 16 + fr) * BK + fq * 8]);
    #pragma unroll
    for (int i = 0; i < 4; ++i)
      bfv[i] = *reinterpret_cast<const bf16x8*>(&Bs[(wn + i * 16 + fr) * BK + fq * 8]);
    #pragma unroll
    for (int mi = 0; mi < 4; ++mi)
      #pragma unroll
      for (int ni = 0; ni < 4; ++ni)
        acc[mi][ni] = __builtin_amdgcn_mfma_f32_16x16x32_bf16(af[mi], bfv[ni], acc[mi][ni], 0, 0, 0);
  }

  // ---- fused epilogue ----
  const int colg = n0 + wn;              // 64-aligned
  const int t = colg >> 10;              // 0=q 1=v 2=k (wave-uniform)
  const int n = (colg & 1023) >> 6;      // head
  const float gamma = 1.0f - exp2f(-5.0f - (float)n);
  const float invf = powf(10000.0f, -(float)fr / 16.0f);
  const ushort_t* imgb = (const ushort_t*)img;
  const float* imgf = (const float*)img;

  #pragma unroll
  for (int mi = 0; mi < 4; ++mi) {
    #pragma unroll
    for (int r = 0; r < 4; ++r) {
      int m = m0 + wm + mi * 16 + fq * 4 + r;
      int b = m / 784, rem = m % 784;
      int h = rem / 28, w = rem % 28;
      size_t ibase = (size_t)m * HID + n * DH + fr;
      float v0 = acc[mi][0][r] + (isbf ? bf2f(imgb[ibase])      : imgf[ibase])      * ALPHA_C;
      float v1 = acc[mi][1][r] + (isbf ? bf2f(imgb[ibase + 16]) : imgf[ibase + 16]) * ALPHA_C;
      float v2 = acc[mi][2][r] + (isbf ? bf2f(imgb[ibase + 32]) : imgf[ibase + 32]) * ALPHA_C;
      float v3 = acc[mi][3][r] + (isbf ? bf2f(imgb[ibase + 48]) : imgf[ibase + 48]) * ALPHA_C;
      if (t == 1) {
        float* vb = vsum + ((((size_t)b * HEADS + n) * BWW + w) * DH) + fr;
        atomicAdd(vb,      v0);
        atomicAdd(vb + 16, v1);
        atomicAdd(vb + 32, v2);
        atomicAdd(vb + 48, v3);
      } else {
        if (t == 2) { v0 *= gamma; v1 *= gamma; v2 *= gamma; v3 *= gamma; }
        float snh, csh, snw, csw;
        __sincosf((float)h * invf, &snh, &csh);
        __sincosf((float)w * invf, &snw, &csw);
        float o0 = v0 * csh - v1 * snh;    // d=fr
        float o1 = v1 * csh + v0 * snh;    // d=fr+16
        float o2 = v2 * csw - v3 * snw;    // d=fr+32
        float o3 = v3 * csw + v2 * snw;    // d=fr+48
        ushort_t* dst = (t == 0 ? qbuf : kbuf) +
            (((((size_t)b * HEADS + n) * BH + h) * BWW + w) * DH) + fr;
        dst[0]  = f2bf(o0);
        dst[16] = f2bf(o1);
        dst[32] = f2bf(o2);
        dst[48] = f2bf(o3);
      }
    }
  }
}

// -------- attention via MFMA: one block per (b,n); 4 waves x 7 h each --------
// S = Q K^T (28x28 pad 32) then out = S @ V (28x64); V y-pad zeroed so S's
// garbage pad-columns contribute exactly 0. GN stats from D regs, direct store.
__global__ __launch_bounds__(256) void attn_k(const ushort_t* __restrict__ qbuf,
                                              const ushort_t* __restrict__ kbuf,
                                              const float* __restrict__ vsum,
                                              ushort_t* __restrict__ out,
                                              float* __restrict__ stats) {
  __shared__ ushort_t Vt[64 * 32];          // Vt[d][y] bf16, y in [0,32), pad zero
  __shared__ ushort_t Sa[4][32 * 32];       // per-wave S in MFMA A-layout
  const int bn = blockIdx.x;                // b*HEADS+n
  const int tid = threadIdx.x;
  const int lane = tid & 63, wv = tid >> 6;
  const int fr = lane & 15, fq = lane >> 4;
  const size_t vbase = (size_t)bn * BWW * DH;

  for (int e = tid; e < 64 * 32; e += 256) {
    int d = e >> 5, y = e & 31;
    Vt[e] = (y < BWW) ? f2bf(vsum[vbase + (size_t)y * DH + d]) : (ushort_t)0;
  }
  __syncthreads();

  bf16x8 bv[4];
  #pragma unroll
  for (int i = 0; i < 4; ++i)
    bv[i] = *reinterpret_cast<const bf16x8*>(&Vt[(i * 16 + fr) * 32 + fq * 8]);

  float lsum = 0.f, lsq = 0.f;
  ushort_t* sa = Sa[wv];

  for (int hi = 0; hi < 7; ++hi) {
    const int h = wv + hi * 4;
    const size_t qb = ((size_t)bn * BH + h) * BWW * DH;

    // S = Q K^T  (rows 28..31 of frags read past this h's region: finite garbage,
    // produces garbage S rows (never stored) and garbage S cols (x V pad = 0))
    f32x4 s[2][2] = {};
    #pragma unroll
    for (int kk = 0; kk < 2; ++kk) {
      bf16x8 qf[2], kf[2];
      #pragma unroll
      for (int t = 0; t < 2; ++t) {
        qf[t] = *reinterpret_cast<const bf16x8*>(qbuf + qb + (size_t)(t * 16 + fr) * DH + kk * 32 + fq * 8);
        kf[t] = *reinterpret_cast<const bf16x8*>(kbuf + qb + (size_t)(t * 16 + fr) * DH + kk * 32 + fq * 8);
      }
      #pragma unroll
      for (int mt = 0; mt < 2; ++mt)
        #pragma unroll
        for (int nt = 0; nt < 2; ++nt)
          s[mt][nt] = __builtin_amdgcn_mfma_f32_16x16x32_bf16(qf[mt], kf[nt], s[mt][nt], 0, 0, 0);
    }

    // C-layout -> A-layout via wave-private LDS tile
    #pragma unroll
    for (int mt = 0; mt < 2; ++mt)
      #pragma unroll
      for (int nt = 0; nt < 2; ++nt)
        #pragma unroll
        for (int r = 0; r < 4; ++r)
          sa[(mt * 16 + fq * 4 + r) * 32 + nt * 16 + fr] = f2bf(s[mt][nt][r]);
    __syncthreads();   // ordering fence (uniform across waves; Sa is wave-private)

    f32x4 o[2][4] = {};
    #pragma unroll
    for (int mt = 0; mt < 2; ++mt) {
      bf16x8 af = *reinterpret_cast<const bf16x8*>(&sa[(mt * 16 + fr) * 32 + fq * 8]);
      #pragma unroll
      for (int nt = 0; nt < 4; ++nt)
        o[mt][nt] = __builtin_amdgcn_mfma_f32_16x16x32_bf16(af, bv[nt], o[mt][nt], 0, 0, 0);
    }

    #pragma unroll
    for (int mt = 0; mt < 2; ++mt)
      #pragma unroll
      for (int r = 0; r < 4; ++r) {
        int w_ = mt * 16 + fq * 4 + r;
        if (w_ < BWW) {
          ushort_t* dst = out + qb + (size_t)w_ * DH + fr;
          #pragma unroll
          for (int nt = 0; nt < 4; ++nt) {
            float v = o[mt][nt][r];
            dst[nt * 16] = f2bf(v);
            lsum += v; lsq += v * v;
          }
        }
      }
  }

  // block reduce -> stats (one block per (b,n): plain store)
  #pragma unroll
  for (int off = 32; off > 0; off >>= 1) {
    lsum += __shfl_down(lsum, off);
    lsq  += __shfl_down(lsq, off);
  }
  __shared__ float rs[4][2];
  if (lane == 0) { rs[wv][0] = lsum; rs[wv][1] = lsq; }
  __syncthreads();
  if (tid == 0) {
    stats[bn * 2]     = rs[0][0] + rs[1][0] + rs[2][0] + rs[3][0];
    stats[bn * 2 + 1] = rs[0][1] + rs[1][1] + rs[2][1] + rs[3][1];
  }
}

// -------- GroupNorm apply + relayout to (b,H,W,hid) bf16 --------
__global__ __launch_bounds__(256) void gn_k(const ushort_t* __restrict__ out,
                                            const float* __restrict__ stats,
                                            const void* __restrict__ gn_w,
                                            const void* __restrict__ gn_b,
                                            const int* __restrict__ flagp,
                                            ushort_t* __restrict__ xo) {
  size_t idx = (size_t)blockIdx.x * 256 + threadIdx.x;   // (b,n,h,w,d)
  int d = idx & 63;
  size_t rest = idx >> 6;
  int w = rest % BWW; rest /= BWW;
  int h = rest % BH;  rest /= BH;
  int n = rest % HEADS;
  int b = (int)(rest / HEADS);
  int isbf = *flagp;
  float gw = isbf ? bf2f(((const ushort_t*)gn_w)[n]) : ((const float*)gn_w)[n];
  float gb = isbf ? bf2f(((const ushort_t*)gn_b)[n]) : ((const float*)gn_b)[n];
  float s  = stats[(b * HEADS + n) * 2];
  float q2 = stats[(b * HEADS + n) * 2 + 1];
  const float Ninv = 1.0f / (float)(BH * BWW * DH);
  float mu = s * Ninv;
  float var = q2 * Ninv - mu * mu;
  float rstd = rsqrtf(var + EPS_C);
  float v = (bf2f(out[idx]) - mu) * rstd * gw + gb;
  size_t dst = ((((size_t)b * BH + h) * BWW + w) * HID) + (size_t)n * DH + d;
  xo[dst] = f2bf(v);
}

// -------- plain GEMM (used for GEMM2), dyn output dtype --------
__global__ __launch_bounds__(256) void gemm_bt_k(const ushort_t* __restrict__ A,
                                                 const ushort_t* __restrict__ Bt,
                                                 void* __restrict__ Cv,
                                                 const int* __restrict__ flagp,
                                                 int M, int N, int K) {
  __shared__ ushort_t As[128 * BK];
  __shared__ ushort_t Bs[128 * BK];
  const int tid = threadIdx.x;
  const int ntile = N / 128;
  const int n0 = (blockIdx.x % ntile) * 128;
  const int m0 = (blockIdx.x / ntile) * 128;
  const int lane = tid & 63;
  const int wave = tid >> 6;
  const int wm = (wave >> 1) * 64;
  const int wn = (wave & 1) * 64;
  const int fr = lane & 15;
  const int fq = lane >> 4;

  f32x4 acc[4][4] = {};
  const int srow = tid >> 2;
  const int skk  = (tid & 3) * 8;

  for (int k0 = 0; k0 < K; k0 += BK) {
    __syncthreads();
    const ushort_t* a0 = A + (size_t)(m0 + srow) * K + k0 + skk;
    const ushort_t* b0 = Bt + (size_t)(n0 + srow) * K + k0 + skk;
    __builtin_amdgcn_global_load_lds((const __attribute__((address_space(1))) unsigned int*)a0,
        (__attribute__((address_space(3))) unsigned int*)(As + tid * 8), 16, 0, 0);
    __builtin_amdgcn_global_load_lds((const __attribute__((address_space(1))) unsigned int*)(a0 + (size_t)64 * K),
        (__attribute__((address_space(3))) unsigned int*)(As + 2048 + tid * 8), 16, 0, 0);
    __builtin_amdgcn_global_load_lds((const __attribute__((address_space(1))) unsigned int*)b0,
        (__attribute__((address_space(3))) unsigned int*)(Bs + tid * 8), 16, 0, 0);
    __builtin_amdgcn_global_load_lds((const __attribute__((address_space(1))) unsigned int*)(b0 + (size_t)64 * K),
        (__attribute__((address_space(3))) unsigned int*)(Bs + 2048 + tid * 8), 16, 0, 0);
    __syncthreads();

    bf16x8 af[4], bfv[4];
    #pragma unroll
    for (int i = 0; i < 4; ++i)
      af[i] = *reinterpret_cast<const bf16x8*>(&As[(wm + i * 16 + fr) * BK + fq * 8]);
    #pragma unroll
    for (int i = 0; i < 4; ++i)
      bfv[i] = *reinterpret_cast<const bf16x8*>(&Bs[(wn + i * 16 + fr) * BK + fq * 8]);
    #pragma unroll
    for (int mi = 0; mi < 4; ++mi)
      #pragma unroll
      for (int ni = 0; ni < 4; ++ni)
        acc[mi][ni] = __builtin_amdgcn_mfma_f32_16x16x32_bf16(af[mi], bfv[ni], acc[mi][ni], 0, 0, 0);
  }

  int isbf = *flagp;
  if (isbf) {
    ushort_t* C = (ushort_t*)Cv;
    #pragma unroll
    for (int mi = 0; mi < 4; ++mi)
      #pragma unroll
      for (int r = 0; r < 4; ++r) {
        int m = m0 + wm + mi * 16 + fq * 4 + r;
        ushort_t* crow = C + (size_t)m * N + n0 + wn + fr;
        #pragma unroll
        for (int ni = 0; ni < 4; ++ni) crow[ni * 16] = f2bf(acc[mi][ni][r]);
      }
  } else {
    float* C = (float*)Cv;
    #pragma unroll
    for (int mi = 0; mi < 4; ++mi)
      #pragma unroll
      for (int r = 0; r < 4; ++r) {
        int m = m0 + wm + mi * 16 + fq * 4 + r;
        float* crow = C + (size_t)m * N + n0 + wn + fr;
        #pragma unroll
        for (int ni = 0; ni < 4; ++ni) crow[ni * 16] = acc[mi][ni][r];
      }
  }
}

// -------- launch --------
extern "C" void kernel_launch(void* const* d_in, const int* in_sizes, int n_in,
                              void* d_out, int out_size, void* d_ws, size_t ws_size,
                              hipStream_t stream) {
  const void* x     = d_in[0];
  const void* img   = d_in[1];
  const void* qkv_w = d_in[2];
  const void* o_w   = d_in[3];
  const void* gn_w  = d_in[4];
  const void* gn_b  = d_in[5];

  char* ws = (char*)d_ws;
  // layout (bytes), peak 217,583,872 (round-3-proven budget):
  ushort_t* x_bf  = (ushort_t*)(ws);                 // 51,380,224; dead after gemm1
  ushort_t* xo    = (ushort_t*)(ws);                 // overlays dead x_bf (written by gn_k)
  ushort_t* qbuf  = (ushort_t*)(ws + 51380224);      // 51,380,224
  ushort_t* kbuf  = (ushort_t*)(ws + 102760448);     // 51,380,224
  ushort_t* attn  = (ushort_t*)(ws + 154140672);     // 51,380,224
  float*    vsum  = (float*)(ws + 205520896);        //  3,670,016 (917,504 floats)
  float*    stats = (float*)(ws + 209190912);        //      4,096
  int*      flag  = (int*)(ws + 209195008);          //        256
  ushort_t* w1T   = (ushort_t*)(ws + 209195264);     //  6,291,456
  ushort_t* w2T   = (ushort_t*)(ws + 215486720);     //  2,097,152 (end 217,583,872)

  detect_k<<<1, 256, 0, stream>>>((const ushort_t*)x, (const ushort_t*)qkv_w, stats, flag);
  zero_k<<<3584, 256, 0, stream>>>(vsum);            // 3584*256 = 917,504 exactly
  conv_x_k<<<12544, 256, 0, stream>>>(x, flag, x_bf, 3211264L);
  transpose_any_k<<<dim3(96, 32), dim3(32, 8), 0, stream>>>(qkv_w, flag, w1T, 1024, 3072);
  transpose_any_k<<<dim3(32, 32), dim3(32, 8), 0, stream>>>(o_w, flag, w2T, 1024, 1024);

  gemm_qkv_k<<<196 * 24, 256, 0, stream>>>(x, x_bf, w1T, img, flag, qbuf, kbuf, vsum);

  attn_k<<<BATCH * HEADS, 256, 0, stream>>>(qbuf, kbuf, vsum, attn, stats);
  gn_k<<<100352, 256, 0, stream>>>(attn, stats, gn_w, gn_b, flag, xo);

  gemm_bt_k<<<196 * 8, 256, 0, stream>>>(xo, w2T, d_out, flag, M_ROWS, 1024, 1024);
}